// Round 8
// baseline (554.228 us; speedup 1.0000x reference)
//
#include <hip/hip_runtime.h>
#include <math.h>

#define TBU 16
#define TB2 16

typedef __attribute__((ext_vector_type(8))) short s8v;
typedef __attribute__((ext_vector_type(4))) short s4v;
typedef __attribute__((ext_vector_type(4))) float f4v;

__device__ __forceinline__ float4 ldg4(const float* p) { return *(const float4*)p; }

// fp32 -> bf16 round-to-nearest-even
__device__ __forceinline__ short f2b(float f) {
    union { float f; unsigned u; } v; v.f = f;
    unsigned r = v.u + 0x7fffu + ((v.u >> 16) & 1u);
    return (short)(r >> 16);
}
__device__ __forceinline__ float b2f(short s) {
    union { unsigned u; float f; } v; v.u = ((unsigned)(unsigned short)s) << 16;
    return v.f;
}
__device__ __forceinline__ s8v pack8(float4 a, float4 b) {
    s8v r;
    r[0] = f2b(a.x); r[1] = f2b(a.y); r[2] = f2b(a.z); r[3] = f2b(a.w);
    r[4] = f2b(b.x); r[5] = f2b(b.y); r[6] = f2b(b.z); r[7] = f2b(b.w);
    return r;
}

// bf16x3 split of 8 fp32 (Ootomo-style): v = hi + mid + lo, each bf16.
struct S3 { s8v h, m, l; };
__device__ __forceinline__ S3 split8(f4v a, f4v b) {
    S3 o;
#pragma unroll
    for (int u = 0; u < 4; ++u) {
        float v = a[u];
        short sh = f2b(v); float r  = v - b2f(sh);
        short sm = f2b(r); float r2 = r - b2f(sm);
        o.h[u] = sh; o.m[u] = sm; o.l[u] = f2b(r2);
        v = b[u];
        sh = f2b(v); r  = v - b2f(sh);
        sm = f2b(r); r2 = r - b2f(sm);
        o.h[u + 4] = sh; o.m[u + 4] = sm; o.l[u + 4] = f2b(r2);
    }
    return o;
}

// 6-term bf16x3 product-sum (small terms first): rel err ~6e-8
__device__ __forceinline__ f4v mfma6(const S3& A, const S3& B, f4v acc) {
    acc = __builtin_amdgcn_mfma_f32_16x16x32_bf16(A.l, B.h, acc, 0, 0, 0);
    acc = __builtin_amdgcn_mfma_f32_16x16x32_bf16(A.m, B.m, acc, 0, 0, 0);
    acc = __builtin_amdgcn_mfma_f32_16x16x32_bf16(A.h, B.l, acc, 0, 0, 0);
    acc = __builtin_amdgcn_mfma_f32_16x16x32_bf16(A.m, B.h, acc, 0, 0, 0);
    acc = __builtin_amdgcn_mfma_f32_16x16x32_bf16(A.h, B.m, acc, 0, 0, 0);
    acc = __builtin_amdgcn_mfma_f32_16x16x32_bf16(A.h, B.h, acc, 0, 0, 0);
    return acc;
}

// ---------------------------------------------------------------------------
// Kernel 1: up router (TB=16, down-style; fp32 reorder-safe — R1/R2 forensics
// proved selection-equivalence) + bf16x3-MFMA experts (R7-verbatim math,
// 4 tokens/wave, X from global) + gelu. h bitwise-identical to R7's h.
// ---------------------------------------------------------------------------
__global__ __launch_bounds__(256, 3) void up_kernel(
    const float* __restrict__ x, const float* __restrict__ Wup,
    const float* __restrict__ Aup, const float* __restrict__ Bup,
    const float* __restrict__ scale_up, const float* __restrict__ bias_up,
    float* __restrict__ h)
{
    // router: wcs [64][68] @0 (17408B) | xcs [16][68] @17408 (4352B) |
    //         lp [4][16][64] @21760 (16384B) | logits [16][64] @38144 (4096B)
    // expert: wt [4 waves][64 p][36 i] fp32 (36864B) aliases wcs..lp (dead).
    __shared__ __align__(16) char smem[42240];
    float* wcs    = (float*)smem;
    float* xcs    = (float*)(smem + 17408);
    float* lp     = (float*)(smem + 21760);
    float* logits = (float*)(smem + 38144);
    float* wt     = (float*)smem;
    __shared__ int   seli[TBU * 2];
    __shared__ float selp[TBU * 2];

    const int tid = threadIdx.x;
    const long long tokbase = (long long)blockIdx.x * TBU;

    // ---- router: logits = x . Wup^T (4 experts/thread, staging /16 tokens) --
    const int e4 = tid & 15, jsl = tid >> 4;   // jsl 0..15
    float r0[16], r1[16], r2[16], r3[16];
#pragma unroll
    for (int t = 0; t < 16; ++t) { r0[t] = 0.f; r1[t] = 0.f; r2[t] = 0.f; r3[t] = 0.f; }

    for (int kc = 0; kc < 1024; kc += 64) {
        __syncthreads();
#pragma unroll
        for (int r = 0; r < 4; ++r) {
            int row = (tid >> 4) + r * 16;
            int col = (tid & 15) * 4;
            *(float4*)&wcs[row * 68 + col] = ldg4(&Wup[row * 1024 + kc + col]);
        }
        {
            int t = tid >> 4, c = (tid & 15) * 4;
            *(float4*)&xcs[t * 68 + c] = ldg4(&x[(tokbase + t) * 1024 + kc + c]);
        }
        __syncthreads();
        const int kk = jsl * 4;
        float4 w0 = *(float4*)&wcs[(e4)      * 68 + kk];
        float4 w1 = *(float4*)&wcs[(e4 + 16) * 68 + kk];
        float4 w2 = *(float4*)&wcs[(e4 + 32) * 68 + kk];
        float4 w3 = *(float4*)&wcs[(e4 + 48) * 68 + kk];
#pragma unroll
        for (int t = 0; t < 16; ++t) {
            float4 hv = *(float4*)&xcs[t * 68 + kk];
            r0[t] += w0.x * hv.x + w0.y * hv.y + w0.z * hv.z + w0.w * hv.w;
            r1[t] += w1.x * hv.x + w1.y * hv.y + w1.z * hv.z + w1.w * hv.w;
            r2[t] += w2.x * hv.x + w2.y * hv.y + w2.z * hv.z + w2.w * hv.w;
            r3[t] += w3.x * hv.x + w3.y * hv.y + w3.z * hv.z + w3.w * hv.w;
        }
    }
    // reduce over the wave's 4 k-slices (lanes xor 16, 32)
#pragma unroll
    for (int t = 0; t < 16; ++t) {
        r0[t] += __shfl_xor(r0[t], 16); r0[t] += __shfl_xor(r0[t], 32);
        r1[t] += __shfl_xor(r1[t], 16); r1[t] += __shfl_xor(r1[t], 32);
        r2[t] += __shfl_xor(r2[t], 16); r2[t] += __shfl_xor(r2[t], 32);
        r3[t] += __shfl_xor(r3[t], 16); r3[t] += __shfl_xor(r3[t], 32);
    }
    {
        const int wv = tid >> 6, g = (tid >> 4) & 3;
        float* dst = &lp[wv * 1024];
        if (g == 0) {
#pragma unroll
            for (int t = 0; t < 16; ++t) dst[t * 64 + e4] = r0[t];
        } else if (g == 1) {
#pragma unroll
            for (int t = 0; t < 16; ++t) dst[t * 64 + 16 + e4] = r1[t];
        } else if (g == 2) {
#pragma unroll
            for (int t = 0; t < 16; ++t) dst[t * 64 + 32 + e4] = r2[t];
        } else {
#pragma unroll
            for (int t = 0; t < 16; ++t) dst[t * 64 + 48 + e4] = r3[t];
        }
    }
    __syncthreads();
#pragma unroll
    for (int q = 0; q < 4; ++q) {
        int pair = tid + q * 256;
        logits[pair] = lp[0 * 1024 + pair] + lp[1 * 1024 + pair] +
                       lp[2 * 1024 + pair] + lp[3 * 1024 + pair];
    }
    __syncthreads();
    if (tid < TBU) {
        const float* lg = &logits[tid * 64];
        float v0 = -1e30f; int i0 = 0;
        for (int q = 0; q < 64; ++q) { float v = lg[q]; if (v > v0) { v0 = v; i0 = q; } }
        float v1 = -1e30f; int i1 = 0;
        for (int q = 0; q < 64; ++q) { if (q == i0) continue; float v = lg[q]; if (v > v1) { v1 = v; i1 = q; } }
        float r = expf(v1 - v0);
        float inv = 1.f / (1.f + r);
        seli[tid * 2] = i0; seli[tid * 2 + 1] = i1;
        selp[tid * 2] = inv; selp[tid * 2 + 1] = r * inv;
    }
    __syncthreads();   // router LDS dead past here; wt aliases it

    // ---- experts: per-wave bf16x3 MFMA, 4 tokens/wave, no barriers ----
    const float sc_up = scale_up[0];
    const int wv = tid >> 6, lane = tid & 63;
    const int m = lane & 15, quad = lane >> 4;
    float* wtw = wt + wv * 2304;     // [64 p][36 i] fp32 per wave
    const f4v zf = {0.f, 0.f, 0.f, 0.f};

#pragma unroll 1
    for (int tt = 0; tt < 4; ++tt) {
        const int t = wv * 4 + tt;
        const long long tok = tokbase + t;
        const float* xrow = x + tok * 1024;   // X [32 i][32 j], global (L2-hot)

        // X fragments: X[i = mt*16 + m][j = quad*8 .. +7]; split hoisted
        f4v xA0 = *(const f4v*)&xrow[(0 * 16 + m) * 32 + quad * 8];
        f4v xA1 = *(const f4v*)&xrow[(0 * 16 + m) * 32 + quad * 8 + 4];
        f4v xB0 = *(const f4v*)&xrow[(1 * 16 + m) * 32 + quad * 8];
        f4v xB1 = *(const f4v*)&xrow[(1 * 16 + m) * 32 + quad * 8 + 4];
        S3 x0 = split8(xA0, xA1);
        S3 x1 = split8(xB0, xB1);

        f4v Y[16];   // [ot 0..3][pt 0..3]
#pragma unroll
        for (int q = 0; q < 16; ++q) Y[q] = zf;

#pragma unroll 1
        for (int ke = 0; ke < 2; ++ke) {
            const int ex = seli[t * 2 + ke];
            const float pw = selp[t * 2 + ke];
            const float* A = Aup + (long long)ex * 2048;  // [64 o][32 i]
            const float* B = Bup + (long long)ex * 2048;  // [64 p][32 j]

            // ---- stage 1: W[i][p] = sum_j X[i][j] B[p][j]  (K=32) ----
            f4v wd[8];   // [mt 0..1][pt 0..3]
#pragma unroll
            for (int pt = 0; pt < 4; ++pt) {
                int base = (pt * 16 + m) * 32 + quad * 8;
                S3 bs = split8(*(const f4v*)(B + base), *(const f4v*)(B + base + 4));
                wd[0 * 4 + pt] = mfma6(x0, bs, zf);
                wd[1 * 4 + pt] = mfma6(x1, bs, zf);
            }
            // write (pw*W)^T fp32: lane holds W[i = mt*16+quad*4+r][p = pt*16+m]
            {
                const f4v pwv = {pw, pw, pw, pw};
#pragma unroll
                for (int mt = 0; mt < 2; ++mt)
#pragma unroll
                    for (int pt = 0; pt < 4; ++pt) {
                        f4v w = wd[mt * 4 + pt] * pwv;
                        *(f4v*)&wtw[(pt * 16 + m) * 36 + mt * 16 + quad * 4] = w;
                    }
            }

            // ---- stage 2: Y[o][p] += sum_i A[o][i] (pw*W)[i][p]  (K=32) ----
#pragma unroll
            for (int pth = 0; pth < 2; ++pth) {
                int p0 = (pth * 2 + 0) * 16 + m;
                int p1 = (pth * 2 + 1) * 16 + m;
                S3 w0 = split8(*(const f4v*)&wtw[p0 * 36 + quad * 8],
                               *(const f4v*)&wtw[p0 * 36 + quad * 8 + 4]);
                S3 w1 = split8(*(const f4v*)&wtw[p1 * 36 + quad * 8],
                               *(const f4v*)&wtw[p1 * 36 + quad * 8 + 4]);
#pragma unroll
                for (int ot = 0; ot < 4; ++ot) {
                    int abase = (ot * 16 + m) * 32 + quad * 8;
                    S3 as = split8(*(const f4v*)(A + abase), *(const f4v*)(A + abase + 4));
                    Y[ot * 4 + pth * 2 + 0] = mfma6(as, w0, Y[ot * 4 + pth * 2 + 0]);
                    Y[ot * 4 + pth * 2 + 1] = mfma6(as, w1, Y[ot * 4 + pth * 2 + 1]);
                }
            }
        }

        // ---- epilogue: Y[o = ot*16+quad*4+r][p = pt*16+m] -> gelu -> h ----
        {
            float* hrow = h + tok * 4096;
#pragma unroll
            for (int ot = 0; ot < 4; ++ot)
#pragma unroll
                for (int r = 0; r < 4; ++r) {
                    int o = ot * 16 + quad * 4 + r;
#pragma unroll
                    for (int pt = 0; pt < 4; ++pt) {
                        int f = o * 64 + pt * 16 + m;
                        float v = Y[ot * 4 + pt][r] * sc_up;
                        float z = v + bias_up[f];
                        hrow[f] = 0.5f * z * (1.0f + erff(z * 0.70710678118654752f));
                    }
                }
        }
    }
}

// ---------------------------------------------------------------------------
// Kernel 2: down router + down experts (bf16 MFMA, per-wave)
// [VERBATIM R0 baseline — measured ~187.5 us]
// ---------------------------------------------------------------------------
__global__ __launch_bounds__(256, 2) void down_kernel(
    const float* __restrict__ h,        // [N][4096]
    const float* __restrict__ Wdn,      // [64][4096]
    const float* __restrict__ Adn,      // [64][32][64]
    const float* __restrict__ Bdn,      // [64][32][64]
    const float* __restrict__ scale_dn, // [1]
    const float* __restrict__ bias_dn,  // [1024]
    float* __restrict__ out)            // [N][1024]
{
    __shared__ __align__(16) float wcs[64 * 68];    // 17.4 KB
    __shared__ __align__(16) float hcs[16 * 68];    // 4.3 KB
    __shared__ __align__(16) float lp[4 * 16 * 64]; // 16.4 KB
    __shared__ __align__(16) float logits[TB2 * 64];
    __shared__ __align__(16) short wt[4][32 * 72];  // per-wave W^T bf16 [p][i]
    __shared__ int   seli[TB2 * 2];
    __shared__ float selp[TB2 * 2];

    const int tid = threadIdx.x;
    const long long tokbase = (long long)blockIdx.x * TB2;

    // ---- down router: 4 experts per thread, k-slice = one float4 ----
    const int e4 = tid & 15, jsl = tid >> 4; // jsl 0..15
    float r0[16], r1[16], r2[16], r3[16];
#pragma unroll
    for (int t = 0; t < 16; ++t) { r0[t] = 0.f; r1[t] = 0.f; r2[t] = 0.f; r3[t] = 0.f; }

    for (int kc = 0; kc < 4096; kc += 64) {
        __syncthreads();
#pragma unroll
        for (int r = 0; r < 4; ++r) {
            int row = (tid >> 4) + r * 16;
            int col = (tid & 15) * 4;
            *(float4*)&wcs[row * 68 + col] = ldg4(&Wdn[row * 4096 + kc + col]);
        }
        {
            int t = tid >> 4, c = (tid & 15) * 4;
            *(float4*)&hcs[t * 68 + c] = ldg4(&h[(tokbase + t) * 4096 + kc + c]);
        }
        __syncthreads();
        const int kk = jsl * 4;
        float4 w0 = *(float4*)&wcs[(e4)      * 68 + kk];
        float4 w1 = *(float4*)&wcs[(e4 + 16) * 68 + kk];
        float4 w2 = *(float4*)&wcs[(e4 + 32) * 68 + kk];
        float4 w3 = *(float4*)&wcs[(e4 + 48) * 68 + kk];
#pragma unroll
        for (int t = 0; t < 16; ++t) {
            float4 hv = *(float4*)&hcs[t * 68 + kk];
            r0[t] += w0.x * hv.x + w0.y * hv.y + w0.z * hv.z + w0.w * hv.w;
            r1[t] += w1.x * hv.x + w1.y * hv.y + w1.z * hv.z + w1.w * hv.w;
            r2[t] += w2.x * hv.x + w2.y * hv.y + w2.z * hv.z + w2.w * hv.w;
            r3[t] += w3.x * hv.x + w3.y * hv.y + w3.z * hv.z + w3.w * hv.w;
        }
    }
    // reduce over the wave's 4 k-slices (lanes xor 16, 32)
#pragma unroll
    for (int t = 0; t < 16; ++t) {
        r0[t] += __shfl_xor(r0[t], 16); r0[t] += __shfl_xor(r0[t], 32);
        r1[t] += __shfl_xor(r1[t], 16); r1[t] += __shfl_xor(r1[t], 32);
        r2[t] += __shfl_xor(r2[t], 16); r2[t] += __shfl_xor(r2[t], 32);
        r3[t] += __shfl_xor(r3[t], 16); r3[t] += __shfl_xor(r3[t], 32);
    }
    {
        const int wv = tid >> 6, g = (tid >> 4) & 3;
        float* dst = &lp[wv * 1024];
        if (g == 0) {
#pragma unroll
            for (int t = 0; t < 16; ++t) dst[t * 64 + e4] = r0[t];
        } else if (g == 1) {
#pragma unroll
            for (int t = 0; t < 16; ++t) dst[t * 64 + 16 + e4] = r1[t];
        } else if (g == 2) {
#pragma unroll
            for (int t = 0; t < 16; ++t) dst[t * 64 + 32 + e4] = r2[t];
        } else {
#pragma unroll
            for (int t = 0; t < 16; ++t) dst[t * 64 + 48 + e4] = r3[t];
        }
    }
    __syncthreads();
#pragma unroll
    for (int q = 0; q < 4; ++q) {
        int pair = tid + q * 256;
        logits[pair] = lp[0 * 1024 + pair] + lp[1 * 1024 + pair] +
                       lp[2 * 1024 + pair] + lp[3 * 1024 + pair];
    }
    __syncthreads();
    if (tid < TB2) {
        const float* lg = &logits[tid * 64];
        float v0 = -1e30f; int i0 = 0;
        for (int q = 0; q < 64; ++q) { float v = lg[q]; if (v > v0) { v0 = v; i0 = q; } }
        float v1 = -1e30f; int i1 = 0;
        for (int q = 0; q < 64; ++q) { if (q == i0) continue; float v = lg[q]; if (v > v1) { v1 = v; i1 = q; } }
        float r = expf(v1 - v0);
        float inv = 1.f / (1.f + r);
        seli[tid * 2] = i0; seli[tid * 2 + 1] = i1;
        selp[tid * 2] = inv; selp[tid * 2 + 1] = r * inv;
    }
    __syncthreads();

    // ---- down experts: per-wave MFMA, no barriers ----
    const float sc_dn = scale_dn[0];
    const int wv = tid >> 6;
    const int lane = tid & 63;
    const int m = lane & 15, quad = lane >> 4;
    short* wtw = &wt[wv][0]; // [32 p][72 i] bf16

    const f4v zf = {0.f, 0.f, 0.f, 0.f};

#pragma unroll 1
    for (int tt = 0; tt < 4; ++tt) {
        const int t = wv * 4 + tt;
        const long long tok = tokbase + t;
        const float* xrow = h + tok * 4096; // X[64 i][64 j], j contiguous

        s8v xf[8];
#pragma unroll
        for (int mt = 0; mt < 4; ++mt)
#pragma unroll
            for (int ks = 0; ks < 2; ++ks) {
                int base = (mt * 16 + m) * 64 + ks * 32 + quad * 8;
                xf[mt * 2 + ks] = pack8(ldg4(xrow + base), ldg4(xrow + base + 4));
            }

        f4v y00 = zf, y01 = zf, y10 = zf, y11 = zf;

        for (int ke = 0; ke < 2; ++ke) {
            const int ex = seli[t * 2 + ke];
            const float pw = selp[t * 2 + ke];
            const float* A = Adn + ex * 2048; // [32 o][64 i]
            const float* B = Bdn + ex * 2048; // [32 p][64 j]

            // ---- stage 1: W[i][p] = sum_j X[i][j] * B[p][j] ----
            f4v wd[8];
#pragma unroll
            for (int ks = 0; ks < 2; ++ks) {
                s8v bf0, bf1;
                {
                    int base = (0 * 16 + m) * 64 + ks * 32 + quad * 8;
                    bf0 = pack8(ldg4(B + base), ldg4(B + base + 4));
                    base = (1 * 16 + m) * 64 + ks * 32 + quad * 8;
                    bf1 = pack8(ldg4(B + base), ldg4(B + base + 4));
                }
#pragma unroll
                for (int mt = 0; mt < 4; ++mt) {
                    wd[mt * 2 + 0] = __builtin_amdgcn_mfma_f32_16x16x32_bf16(
                        xf[mt * 2 + ks], bf0, ks == 0 ? zf : wd[mt * 2 + 0], 0, 0, 0);
                    wd[mt * 2 + 1] = __builtin_amdgcn_mfma_f32_16x16x32_bf16(
                        xf[mt * 2 + ks], bf1, ks == 0 ? zf : wd[mt * 2 + 1], 0, 0, 0);
                }
            }
#pragma unroll
            for (int mt = 0; mt < 4; ++mt)
#pragma unroll
                for (int pt = 0; pt < 2; ++pt) {
                    f4v w = wd[mt * 2 + pt];
                    s4v s;
                    s[0] = f2b(w[0] * pw); s[1] = f2b(w[1] * pw);
                    s[2] = f2b(w[2] * pw); s[3] = f2b(w[3] * pw);
                    *(s4v*)&wtw[(pt * 16 + m) * 72 + mt * 16 + quad * 4] = s;
                }

            // ---- stage 2: Y[o][p] += sum_i A[o][i] * (pw*W)[i][p] ----
#pragma unroll
            for (int ks = 0; ks < 2; ++ks) {
                s8v wb0 = *(s8v*)&wtw[(0 * 16 + m) * 72 + ks * 32 + quad * 8];
                s8v wb1 = *(s8v*)&wtw[(1 * 16 + m) * 72 + ks * 32 + quad * 8];
                s8v af0, af1;
                {
                    int base = (0 * 16 + m) * 64 + ks * 32 + quad * 8;
                    af0 = pack8(ldg4(A + base), ldg4(A + base + 4));
                    base = (1 * 16 + m) * 64 + ks * 32 + quad * 8;
                    af1 = pack8(ldg4(A + base), ldg4(A + base + 4));
                }
                y00 = __builtin_amdgcn_mfma_f32_16x16x32_bf16(af0, wb0, y00, 0, 0, 0);
                y01 = __builtin_amdgcn_mfma_f32_16x16x32_bf16(af0, wb1, y01, 0, 0, 0);
                y10 = __builtin_amdgcn_mfma_f32_16x16x32_bf16(af1, wb0, y10, 0, 0, 0);
                y11 = __builtin_amdgcn_mfma_f32_16x16x32_bf16(af1, wb1, y11, 0, 0, 0);
            }
        }

        float* orow = out + tok * 1024;
#pragma unroll
        for (int r = 0; r < 4; ++r) {
            int o0 = quad * 4 + r;
            int f00 = o0 * 32 + m;
            orow[f00]            = y00[r] * sc_dn + bias_dn[f00];
            orow[f00 + 16]       = y01[r] * sc_dn + bias_dn[f00 + 16];
            int f10 = (o0 + 16) * 32 + m;
            orow[f10]            = y10[r] * sc_dn + bias_dn[f10];
            orow[f10 + 16]       = y11[r] * sc_dn + bias_dn[f10 + 16];
        }
    }
}

extern "C" void kernel_launch(void* const* d_in, const int* in_sizes, int n_in,
                              void* d_out, int out_size, void* d_ws, size_t ws_size,
                              hipStream_t stream) {
    const float* x   = (const float*)d_in[0];
    const float* Wup = (const float*)d_in[1];
    const float* Aup = (const float*)d_in[2];
    const float* Bup = (const float*)d_in[3];
    const float* scu = (const float*)d_in[4];
    const float* biu = (const float*)d_in[5];
    const float* Wdn = (const float*)d_in[6];
    const float* Adn = (const float*)d_in[7];
    const float* Bdn = (const float*)d_in[8];
    const float* scd = (const float*)d_in[9];
    const float* bid = (const float*)d_in[10];
    float* out = (float*)d_out;
    float* h   = (float*)d_ws;   // [N][4096] fp32 = 128 MB for N=8192

    const int N = in_sizes[0] / 1024;

    hipLaunchKernelGGL(up_kernel, dim3(N / TBU), dim3(256), 0, stream,
                       x, Wup, Aup, Bup, scu, biu, h);
    hipLaunchKernelGGL(down_kernel, dim3(N / TB2), dim3(256), 0, stream,
                       h, Wdn, Adn, Bdn, scd, bid, out);
}

// Round 9
// 412.696 us; speedup vs baseline: 1.3429x; 1.3429x over previous
//
#include <hip/hip_runtime.h>
#include <math.h>

#define TB1 4
#define TB2 16

typedef __attribute__((ext_vector_type(8))) short s8v;
typedef __attribute__((ext_vector_type(4))) short s4v;
typedef __attribute__((ext_vector_type(4))) float f4v;

__device__ __forceinline__ float4 ldg4(const float* p) { return *(const float4*)p; }

// fp32 -> bf16 round-to-nearest-even
__device__ __forceinline__ short f2b(float f) {
    union { float f; unsigned u; } v; v.f = f;
    unsigned r = v.u + 0x7fffu + ((v.u >> 16) & 1u);
    return (short)(r >> 16);
}
__device__ __forceinline__ float b2f(short s) {
    union { unsigned u; float f; } v; v.u = ((unsigned)(unsigned short)s) << 16;
    return v.f;
}
__device__ __forceinline__ s8v pack8(float4 a, float4 b) {
    s8v r;
    r[0] = f2b(a.x); r[1] = f2b(a.y); r[2] = f2b(a.z); r[3] = f2b(a.w);
    r[4] = f2b(b.x); r[5] = f2b(b.y); r[6] = f2b(b.z); r[7] = f2b(b.w);
    return r;
}

// bf16x3 split of 8 fp32 (Ootomo-style): v = hi + mid + lo, each bf16.
struct S3 { s8v h, m, l; };
__device__ __forceinline__ S3 split8(f4v a, f4v b) {
    S3 o;
#pragma unroll
    for (int u = 0; u < 4; ++u) {
        float v = a[u];
        short sh = f2b(v); float r  = v - b2f(sh);
        short sm = f2b(r); float r2 = r - b2f(sm);
        o.h[u] = sh; o.m[u] = sm; o.l[u] = f2b(r2);
        v = b[u];
        sh = f2b(v); r  = v - b2f(sh);
        sm = f2b(r); r2 = r - b2f(sm);
        o.h[u + 4] = sh; o.m[u + 4] = sm; o.l[u + 4] = f2b(r2);
    }
    return o;
}

// 6-term bf16x3 product-sum (small terms first): rel err ~6e-8
__device__ __forceinline__ f4v mfma6(const S3& A, const S3& B, f4v acc) {
    acc = __builtin_amdgcn_mfma_f32_16x16x32_bf16(A.l, B.h, acc, 0, 0, 0);
    acc = __builtin_amdgcn_mfma_f32_16x16x32_bf16(A.m, B.m, acc, 0, 0, 0);
    acc = __builtin_amdgcn_mfma_f32_16x16x32_bf16(A.h, B.l, acc, 0, 0, 0);
    acc = __builtin_amdgcn_mfma_f32_16x16x32_bf16(A.m, B.h, acc, 0, 0, 0);
    acc = __builtin_amdgcn_mfma_f32_16x16x32_bf16(A.h, B.m, acc, 0, 0, 0);
    acc = __builtin_amdgcn_mfma_f32_16x16x32_bf16(A.h, B.h, acc, 0, 0, 0);
    return acc;
}

// ---------------------------------------------------------------------------
// Kernel 1 [R7 structure, verified 176us]: up router (TB1=4, bitwise logits,
// T14 prefetch) + bf16x3-MFMA experts (1 token/wave) + gelu.
// ONLY change vs R7: epilogue routes Y through per-wave LDS (wtw, free after
// stage 2) and stores h as contiguous float4 — fixes the 2x write
// amplification (partial-line writeback + RFO) the scattered scalar stores
// caused (R7 WRITE 253MB vs 128MB of h; R6 coalesced epilogue measured
// exactly 131072KB). Per-element arithmetic identical => h bitwise == R7.
// ---------------------------------------------------------------------------
__global__ __launch_bounds__(256, 3) void up_kernel(
    const float* __restrict__ x, const float* __restrict__ Wup,
    const float* __restrict__ Aup, const float* __restrict__ Bup,
    const float* __restrict__ scale_up, const float* __restrict__ bias_up,
    float* __restrict__ h)
{
    // router: xs@0 (16384B) | wcs@16384 (17408B) | lp@33792 (4096B) |
    //         logits@37888 (1024B)  = 38912B
    // expert: wt@0 = [4 waves][64 p][36 i] fp32 (36864B) aliases xs..lp.
    __shared__ __align__(16) char smem[38912];
    float* xs     = (float*)smem;
    float* wcs    = (float*)(smem + 16384);
    float* lp     = (float*)(smem + 33792);
    float* logits = (float*)(smem + 37888);
    float* wt     = (float*)smem;
    __shared__ int   seli[TB1 * 2];
    __shared__ float selp[TB1 * 2];

    const int tid = threadIdx.x;
    const long long blockTok = (long long)blockIdx.x * TB1;

    // ---- stage x rows (verbatim) ----
    {
        const float* src = x + blockTok * 1024;
#pragma unroll
        for (int q = 0; q < TB1; ++q) {
            int flat = tid * 4 + q * 1024;
            *(float4*)&xs[flat] = ldg4(src + flat);
        }
    }

    // ---- router: logits = x . Wup^T (bitwise; T14 prefetch) ----
    float racc0[TB1] = {0.f, 0.f, 0.f, 0.f};
    float racc1[TB1] = {0.f, 0.f, 0.f, 0.f};
    const int e2 = tid & 31, jsl = tid >> 5;
    const int prow = tid >> 4, pcol = (tid & 15) * 4;

    float4 qw0 = ldg4(&Wup[(prow +  0) * 1024 + 0 + pcol]);
    float4 qw1 = ldg4(&Wup[(prow + 16) * 1024 + 0 + pcol]);
    float4 qw2 = ldg4(&Wup[(prow + 32) * 1024 + 0 + pcol]);
    float4 qw3 = ldg4(&Wup[(prow + 48) * 1024 + 0 + pcol]);

    for (int kc = 0; kc < 1024; kc += 64) {
        __syncthreads();
        *(float4*)&wcs[(prow +  0) * 68 + pcol] = qw0;
        *(float4*)&wcs[(prow + 16) * 68 + pcol] = qw1;
        *(float4*)&wcs[(prow + 32) * 68 + pcol] = qw2;
        *(float4*)&wcs[(prow + 48) * 68 + pcol] = qw3;
        {
            int nkc = (kc + 64 < 1024) ? kc + 64 : 0;  // last prefetch discarded
            qw0 = ldg4(&Wup[(prow +  0) * 1024 + nkc + pcol]);
            qw1 = ldg4(&Wup[(prow + 16) * 1024 + nkc + pcol]);
            qw2 = ldg4(&Wup[(prow + 32) * 1024 + nkc + pcol]);
            qw3 = ldg4(&Wup[(prow + 48) * 1024 + nkc + pcol]);
        }
        __syncthreads();
#pragma unroll
        for (int ks = 0; ks < 2; ++ks) {
            int kk = jsl * 8 + ks * 4;
            float4 w0 = *(float4*)&wcs[e2 * 68 + kk];
            float4 w1 = *(float4*)&wcs[(e2 + 32) * 68 + kk];
#pragma unroll
            for (int t = 0; t < TB1; ++t) {
                float4 xv = *(float4*)&xs[t * 1024 + kc + kk];
                racc0[t] += w0.x * xv.x + w0.y * xv.y + w0.z * xv.z + w0.w * xv.w;
                racc1[t] += w1.x * xv.x + w1.y * xv.y + w1.z * xv.z + w1.w * xv.w;
            }
        }
    }
#pragma unroll
    for (int t = 0; t < TB1; ++t) {
        racc0[t] += __shfl_xor(racc0[t], 32);
        racc1[t] += __shfl_xor(racc1[t], 32);
    }
    {
        const int wv = tid >> 6;
        if ((tid & 32) == 0) {
#pragma unroll
            for (int t = 0; t < TB1; ++t) {
                lp[(wv * TB1 + t) * 64 + e2]      = racc0[t];
                lp[(wv * TB1 + t) * 64 + e2 + 32] = racc1[t];
            }
        }
    }
    __syncthreads();
    logits[tid] = lp[0 * 256 + tid] + lp[1 * 256 + tid] + lp[2 * 256 + tid] + lp[3 * 256 + tid];
    __syncthreads();
    if (tid < TB1) {
        const float* lg = &logits[tid * 64];
        float v0 = -1e30f; int i0 = 0;
        for (int q = 0; q < 64; ++q) { float v = lg[q]; if (v > v0) { v0 = v; i0 = q; } }
        float v1 = -1e30f; int i1 = 0;
        for (int q = 0; q < 64; ++q) { if (q == i0) continue; float v = lg[q]; if (v > v1) { v1 = v; i1 = q; } }
        float r = expf(v1 - v0);
        float inv = 1.f / (1.f + r);
        seli[tid * 2] = i0; seli[tid * 2 + 1] = i1;
        selp[tid * 2] = inv; selp[tid * 2 + 1] = r * inv;
    }
    __syncthreads();

    // ---- experts: per-wave bf16x3 MFMA, 1 token/wave ----
    const float sc_up = scale_up[0];
    const int wv = tid >> 6, lane = tid & 63;
    const int m = lane & 15, quad = lane >> 4;
    const long long tok = blockTok + wv;
    float* wtw = wt + wv * 2304;     // [64 p][36 i] fp32 per wave

    // X fp32 fragments from xs (before wt aliases it)
    const float* xrow = &xs[wv * 1024];
    f4v xA0 = *(const f4v*)&xrow[(0 * 16 + m) * 32 + quad * 8];
    f4v xA1 = *(const f4v*)&xrow[(0 * 16 + m) * 32 + quad * 8 + 4];
    f4v xB0 = *(const f4v*)&xrow[(1 * 16 + m) * 32 + quad * 8];
    f4v xB1 = *(const f4v*)&xrow[(1 * 16 + m) * 32 + quad * 8 + 4];
    __syncthreads();   // xs dead; wt region free for expert phase

    const f4v zf = {0.f, 0.f, 0.f, 0.f};
    f4v Y[16];   // [ot 0..3][pt 0..3]
#pragma unroll
    for (int q = 0; q < 16; ++q) Y[q] = zf;

#pragma unroll 1
    for (int ke = 0; ke < 2; ++ke) {
        const int ex = seli[wv * 2 + ke];
        const float pw = selp[wv * 2 + ke];
        const float* A = Aup + (long long)ex * 2048;  // [64 o][32 i]
        const float* B = Bup + (long long)ex * 2048;  // [64 p][32 j]

        S3 x0 = split8(xA0, xA1);
        S3 x1 = split8(xB0, xB1);

        // ---- stage 1: W[i][p] = sum_j X[i][j] B[p][j]  (K=32) ----
        f4v wd[8];   // [mt 0..1][pt 0..3]
#pragma unroll
        for (int pt = 0; pt < 4; ++pt) {
            int base = (pt * 16 + m) * 32 + quad * 8;
            S3 bs = split8(*(const f4v*)(B + base), *(const f4v*)(B + base + 4));
            wd[0 * 4 + pt] = mfma6(x0, bs, zf);
            wd[1 * 4 + pt] = mfma6(x1, bs, zf);
        }
        // write (pw*W)^T fp32: lane holds W[i = mt*16+quad*4+r][p = pt*16+m]
        {
            const f4v pwv = {pw, pw, pw, pw};
#pragma unroll
            for (int mt = 0; mt < 2; ++mt)
#pragma unroll
                for (int pt = 0; pt < 4; ++pt) {
                    f4v w = wd[mt * 4 + pt] * pwv;
                    *(f4v*)&wtw[(pt * 16 + m) * 36 + mt * 16 + quad * 4] = w;
                }
        }

        // ---- stage 2: Y[o][p] += sum_i A[o][i] (pw*W)[i][p]  (K=32) ----
#pragma unroll
        for (int pth = 0; pth < 2; ++pth) {
            int p0 = (pth * 2 + 0) * 16 + m;
            int p1 = (pth * 2 + 1) * 16 + m;
            S3 w0 = split8(*(const f4v*)&wtw[p0 * 36 + quad * 8],
                           *(const f4v*)&wtw[p0 * 36 + quad * 8 + 4]);
            S3 w1 = split8(*(const f4v*)&wtw[p1 * 36 + quad * 8],
                           *(const f4v*)&wtw[p1 * 36 + quad * 8 + 4]);
#pragma unroll
            for (int ot = 0; ot < 4; ++ot) {
                int abase = (ot * 16 + m) * 32 + quad * 8;
                S3 as = split8(*(const f4v*)(A + abase), *(const f4v*)(A + abase + 4));
                Y[ot * 4 + pth * 2 + 0] = mfma6(as, w0, Y[ot * 4 + pth * 2 + 0]);
                Y[ot * 4 + pth * 2 + 1] = mfma6(as, w1, Y[ot * 4 + pth * 2 + 1]);
            }
        }
    }

    // ---- epilogue: coalesced via per-wave LDS transpose (wtw free now) ----
    // Two o-halves of 32 rows: scatter Y*sc into wtw [32][68], then read back
    // and store contiguous float4 (1KB/instr/wave). Same-wave ds ordering, no
    // barrier. Per-element math identical to R7 => h bitwise-identical.
    {
        float* hrow = h + tok * 4096;
#pragma unroll 1
        for (int oh = 0; oh < 2; ++oh) {
#pragma unroll
            for (int oti = 0; oti < 2; ++oti) {
                int ot = oh * 2 + oti;
#pragma unroll
                for (int r = 0; r < 4; ++r) {
                    int ol = oti * 16 + quad * 4 + r;
#pragma unroll
                    for (int pt = 0; pt < 4; ++pt)
                        wtw[ol * 68 + pt * 16 + m] = Y[ot * 4 + pt][r] * sc_up;
                }
            }
#pragma unroll
            for (int it = 0; it < 8; ++it) {
                int fl = it * 256 + lane * 4;
                int ol = fl >> 6, p = fl & 63;
                f4v v = *(const f4v*)&wtw[ol * 68 + p];
                float4 bb = ldg4(&bias_up[oh * 2048 + fl]);
                f4v g;
                float z;
                z = v[0] + bb.x; g[0] = 0.5f * z * (1.0f + erff(z * 0.70710678118654752f));
                z = v[1] + bb.y; g[1] = 0.5f * z * (1.0f + erff(z * 0.70710678118654752f));
                z = v[2] + bb.z; g[2] = 0.5f * z * (1.0f + erff(z * 0.70710678118654752f));
                z = v[3] + bb.w; g[3] = 0.5f * z * (1.0f + erff(z * 0.70710678118654752f));
                *(f4v*)&hrow[oh * 2048 + fl] = g;
            }
        }
    }
}

// ---------------------------------------------------------------------------
// Kernel 2: down router + down experts (bf16 MFMA, per-wave)
// [VERBATIM R0 baseline — measured ~187.5 us]
// ---------------------------------------------------------------------------
__global__ __launch_bounds__(256, 2) void down_kernel(
    const float* __restrict__ h,        // [N][4096]
    const float* __restrict__ Wdn,      // [64][4096]
    const float* __restrict__ Adn,      // [64][32][64]
    const float* __restrict__ Bdn,      // [64][32][64]
    const float* __restrict__ scale_dn, // [1]
    const float* __restrict__ bias_dn,  // [1024]
    float* __restrict__ out)            // [N][1024]
{
    __shared__ __align__(16) float wcs[64 * 68];    // 17.4 KB
    __shared__ __align__(16) float hcs[16 * 68];    // 4.3 KB
    __shared__ __align__(16) float lp[4 * 16 * 64]; // 16.4 KB
    __shared__ __align__(16) float logits[TB2 * 64];
    __shared__ __align__(16) short wt[4][32 * 72];  // per-wave W^T bf16 [p][i]
    __shared__ int   seli[TB2 * 2];
    __shared__ float selp[TB2 * 2];

    const int tid = threadIdx.x;
    const long long tokbase = (long long)blockIdx.x * TB2;

    // ---- down router: 4 experts per thread, k-slice = one float4 ----
    const int e4 = tid & 15, jsl = tid >> 4; // jsl 0..15
    float r0[16], r1[16], r2[16], r3[16];
#pragma unroll
    for (int t = 0; t < 16; ++t) { r0[t] = 0.f; r1[t] = 0.f; r2[t] = 0.f; r3[t] = 0.f; }

    for (int kc = 0; kc < 4096; kc += 64) {
        __syncthreads();
#pragma unroll
        for (int r = 0; r < 4; ++r) {
            int row = (tid >> 4) + r * 16;
            int col = (tid & 15) * 4;
            *(float4*)&wcs[row * 68 + col] = ldg4(&Wdn[row * 4096 + kc + col]);
        }
        {
            int t = tid >> 4, c = (tid & 15) * 4;
            *(float4*)&hcs[t * 68 + c] = ldg4(&h[(tokbase + t) * 4096 + kc + c]);
        }
        __syncthreads();
        const int kk = jsl * 4;
        float4 w0 = *(float4*)&wcs[(e4)      * 68 + kk];
        float4 w1 = *(float4*)&wcs[(e4 + 16) * 68 + kk];
        float4 w2 = *(float4*)&wcs[(e4 + 32) * 68 + kk];
        float4 w3 = *(float4*)&wcs[(e4 + 48) * 68 + kk];
#pragma unroll
        for (int t = 0; t < 16; ++t) {
            float4 hv = *(float4*)&hcs[t * 68 + kk];
            r0[t] += w0.x * hv.x + w0.y * hv.y + w0.z * hv.z + w0.w * hv.w;
            r1[t] += w1.x * hv.x + w1.y * hv.y + w1.z * hv.z + w1.w * hv.w;
            r2[t] += w2.x * hv.x + w2.y * hv.y + w2.z * hv.z + w2.w * hv.w;
            r3[t] += w3.x * hv.x + w3.y * hv.y + w3.z * hv.z + w3.w * hv.w;
        }
    }
    // reduce over the wave's 4 k-slices (lanes xor 16, 32)
#pragma unroll
    for (int t = 0; t < 16; ++t) {
        r0[t] += __shfl_xor(r0[t], 16); r0[t] += __shfl_xor(r0[t], 32);
        r1[t] += __shfl_xor(r1[t], 16); r1[t] += __shfl_xor(r1[t], 32);
        r2[t] += __shfl_xor(r2[t], 16); r2[t] += __shfl_xor(r2[t], 32);
        r3[t] += __shfl_xor(r3[t], 16); r3[t] += __shfl_xor(r3[t], 32);
    }
    {
        const int wv = tid >> 6, g = (tid >> 4) & 3;
        float* dst = &lp[wv * 1024];
        if (g == 0) {
#pragma unroll
            for (int t = 0; t < 16; ++t) dst[t * 64 + e4] = r0[t];
        } else if (g == 1) {
#pragma unroll
            for (int t = 0; t < 16; ++t) dst[t * 64 + 16 + e4] = r1[t];
        } else if (g == 2) {
#pragma unroll
            for (int t = 0; t < 16; ++t) dst[t * 64 + 32 + e4] = r2[t];
        } else {
#pragma unroll
            for (int t = 0; t < 16; ++t) dst[t * 64 + 48 + e4] = r3[t];
        }
    }
    __syncthreads();
#pragma unroll
    for (int q = 0; q < 4; ++q) {
        int pair = tid + q * 256;
        logits[pair] = lp[0 * 1024 + pair] + lp[1 * 1024 + pair] +
                       lp[2 * 1024 + pair] + lp[3 * 1024 + pair];
    }
    __syncthreads();
    if (tid < TB2) {
        const float* lg = &logits[tid * 64];
        float v0 = -1e30f; int i0 = 0;
        for (int q = 0; q < 64; ++q) { float v = lg[q]; if (v > v0) { v0 = v; i0 = q; } }
        float v1 = -1e30f; int i1 = 0;
        for (int q = 0; q < 64; ++q) { if (q == i0) continue; float v = lg[q]; if (v > v1) { v1 = v; i1 = q; } }
        float r = expf(v1 - v0);
        float inv = 1.f / (1.f + r);
        seli[tid * 2] = i0; seli[tid * 2 + 1] = i1;
        selp[tid * 2] = inv; selp[tid * 2 + 1] = r * inv;
    }
    __syncthreads();

    // ---- down experts: per-wave MFMA, no barriers ----
    const float sc_dn = scale_dn[0];
    const int wv = tid >> 6;
    const int lane = tid & 63;
    const int m = lane & 15, quad = lane >> 4;
    short* wtw = &wt[wv][0]; // [32 p][72 i] bf16

    const f4v zf = {0.f, 0.f, 0.f, 0.f};

#pragma unroll 1
    for (int tt = 0; tt < 4; ++tt) {
        const int t = wv * 4 + tt;
        const long long tok = tokbase + t;
        const float* xrow = h + tok * 4096; // X[64 i][64 j], j contiguous

        s8v xf[8];
#pragma unroll
        for (int mt = 0; mt < 4; ++mt)
#pragma unroll
            for (int ks = 0; ks < 2; ++ks) {
                int base = (mt * 16 + m) * 64 + ks * 32 + quad * 8;
                xf[mt * 2 + ks] = pack8(ldg4(xrow + base), ldg4(xrow + base + 4));
            }

        f4v y00 = zf, y01 = zf, y10 = zf, y11 = zf;

        for (int ke = 0; ke < 2; ++ke) {
            const int ex = seli[t * 2 + ke];
            const float pw = selp[t * 2 + ke];
            const float* A = Adn + ex * 2048; // [32 o][64 i]
            const float* B = Bdn + ex * 2048; // [32 p][64 j]

            // ---- stage 1: W[i][p] = sum_j X[i][j] * B[p][j] ----
            f4v wd[8];
#pragma unroll
            for (int ks = 0; ks < 2; ++ks) {
                s8v bf0, bf1;
                {
                    int base = (0 * 16 + m) * 64 + ks * 32 + quad * 8;
                    bf0 = pack8(ldg4(B + base), ldg4(B + base + 4));
                    base = (1 * 16 + m) * 64 + ks * 32 + quad * 8;
                    bf1 = pack8(ldg4(B + base), ldg4(B + base + 4));
                }
#pragma unroll
                for (int mt = 0; mt < 4; ++mt) {
                    wd[mt * 2 + 0] = __builtin_amdgcn_mfma_f32_16x16x32_bf16(
                        xf[mt * 2 + ks], bf0, ks == 0 ? zf : wd[mt * 2 + 0], 0, 0, 0);
                    wd[mt * 2 + 1] = __builtin_amdgcn_mfma_f32_16x16x32_bf16(
                        xf[mt * 2 + ks], bf1, ks == 0 ? zf : wd[mt * 2 + 1], 0, 0, 0);
                }
            }
#pragma unroll
            for (int mt = 0; mt < 4; ++mt)
#pragma unroll
                for (int pt = 0; pt < 2; ++pt) {
                    f4v w = wd[mt * 2 + pt];
                    s4v s;
                    s[0] = f2b(w[0] * pw); s[1] = f2b(w[1] * pw);
                    s[2] = f2b(w[2] * pw); s[3] = f2b(w[3] * pw);
                    *(s4v*)&wtw[(pt * 16 + m) * 72 + mt * 16 + quad * 4] = s;
                }

            // ---- stage 2: Y[o][p] += sum_i A[o][i] * (pw*W)[i][p] ----
#pragma unroll
            for (int ks = 0; ks < 2; ++ks) {
                s8v wb0 = *(s8v*)&wtw[(0 * 16 + m) * 72 + ks * 32 + quad * 8];
                s8v wb1 = *(s8v*)&wtw[(1 * 16 + m) * 72 + ks * 32 + quad * 8];
                s8v af0, af1;
                {
                    int base = (0 * 16 + m) * 64 + ks * 32 + quad * 8;
                    af0 = pack8(ldg4(A + base), ldg4(A + base + 4));
                    base = (1 * 16 + m) * 64 + ks * 32 + quad * 8;
                    af1 = pack8(ldg4(A + base), ldg4(A + base + 4));
                }
                y00 = __builtin_amdgcn_mfma_f32_16x16x32_bf16(af0, wb0, y00, 0, 0, 0);
                y01 = __builtin_amdgcn_mfma_f32_16x16x32_bf16(af0, wb1, y01, 0, 0, 0);
                y10 = __builtin_amdgcn_mfma_f32_16x16x32_bf16(af1, wb0, y10, 0, 0, 0);
                y11 = __builtin_amdgcn_mfma_f32_16x16x32_bf16(af1, wb1, y11, 0, 0, 0);
            }
        }

        float* orow = out + tok * 1024;
#pragma unroll
        for (int r = 0; r < 4; ++r) {
            int o0 = quad * 4 + r;
            int f00 = o0 * 32 + m;
            orow[f00]            = y00[r] * sc_dn + bias_dn[f00];
            orow[f00 + 16]       = y01[r] * sc_dn + bias_dn[f00 + 16];
            int f10 = (o0 + 16) * 32 + m;
            orow[f10]            = y10[r] * sc_dn + bias_dn[f10];
            orow[f10 + 16]       = y11[r] * sc_dn + bias_dn[f10 + 16];
        }
    }
}

extern "C" void kernel_launch(void* const* d_in, const int* in_sizes, int n_in,
                              void* d_out, int out_size, void* d_ws, size_t ws_size,
                              hipStream_t stream) {
    const float* x   = (const float*)d_in[0];
    const float* Wup = (const float*)d_in[1];
    const float* Aup = (const float*)d_in[2];
    const float* Bup = (const float*)d_in[3];
    const float* scu = (const float*)d_in[4];
    const float* biu = (const float*)d_in[5];
    const float* Wdn = (const float*)d_in[6];
    const float* Adn = (const float*)d_in[7];
    const float* Bdn = (const float*)d_in[8];
    const float* scd = (const float*)d_in[9];
    const float* bid = (const float*)d_in[10];
    float* out = (float*)d_out;
    float* h   = (float*)d_ws;   // [N][4096] fp32 = 128 MB for N=8192

    const int N = in_sizes[0] / 1024;

    hipLaunchKernelGGL(up_kernel, dim3(N / TB1), dim3(256), 0, stream,
                       x, Wup, Aup, Bup, scu, biu, h);
    hipLaunchKernelGGL(down_kernel, dim3(N / TB2), dim3(256), 0, stream,
                       h, Wdn, Adn, Bdn, scd, bid, out);
}

// Round 10
// 368.205 us; speedup vs baseline: 1.5052x; 1.1208x over previous
//
#include <hip/hip_runtime.h>
#include <math.h>

#define TB1 4
#define TB2 16

typedef __attribute__((ext_vector_type(8))) short s8v;
typedef __attribute__((ext_vector_type(4))) short s4v;
typedef __attribute__((ext_vector_type(4))) float f4v;

__device__ __forceinline__ float4 ldg4(const float* p) { return *(const float4*)p; }

// fp32 -> bf16 round-to-nearest-even
__device__ __forceinline__ short f2b(float f) {
    union { float f; unsigned u; } v; v.f = f;
    unsigned r = v.u + 0x7fffu + ((v.u >> 16) & 1u);
    return (short)(r >> 16);
}
__device__ __forceinline__ float b2f(short s) {
    union { unsigned u; float f; } v; v.u = ((unsigned)(unsigned short)s) << 16;
    return v.f;
}
__device__ __forceinline__ s8v pack8(float4 a, float4 b) {
    s8v r;
    r[0] = f2b(a.x); r[1] = f2b(a.y); r[2] = f2b(a.z); r[3] = f2b(a.w);
    r[4] = f2b(b.x); r[5] = f2b(b.y); r[6] = f2b(b.z); r[7] = f2b(b.w);
    return r;
}

// bf16x3 split of 8 fp32 (Ootomo-style): v = hi + mid + lo, each bf16.
struct S3 { s8v h, m, l; };
__device__ __forceinline__ S3 split8(f4v a, f4v b) {
    S3 o;
#pragma unroll
    for (int u = 0; u < 4; ++u) {
        float v = a[u];
        short sh = f2b(v); float r  = v - b2f(sh);
        short sm = f2b(r); float r2 = r - b2f(sm);
        o.h[u] = sh; o.m[u] = sm; o.l[u] = f2b(r2);
        v = b[u];
        sh = f2b(v); r  = v - b2f(sh);
        sm = f2b(r); r2 = r - b2f(sm);
        o.h[u + 4] = sh; o.m[u + 4] = sm; o.l[u + 4] = f2b(r2);
    }
    return o;
}

// 6-term bf16x3 product-sum (small terms first): rel err ~6e-8
__device__ __forceinline__ f4v mfma6(const S3& A, const S3& B, f4v acc) {
    acc = __builtin_amdgcn_mfma_f32_16x16x32_bf16(A.l, B.h, acc, 0, 0, 0);
    acc = __builtin_amdgcn_mfma_f32_16x16x32_bf16(A.m, B.m, acc, 0, 0, 0);
    acc = __builtin_amdgcn_mfma_f32_16x16x32_bf16(A.h, B.l, acc, 0, 0, 0);
    acc = __builtin_amdgcn_mfma_f32_16x16x32_bf16(A.m, B.h, acc, 0, 0, 0);
    acc = __builtin_amdgcn_mfma_f32_16x16x32_bf16(A.h, B.m, acc, 0, 0, 0);
    acc = __builtin_amdgcn_mfma_f32_16x16x32_bf16(A.h, B.h, acc, 0, 0, 0);
    return acc;
}

// ---------------------------------------------------------------------------
// Kernel 1 [R7 structure]: up router (TB1=4, bitwise logits, T14 prefetch) +
// bf16x3-MFMA experts (1 token/wave) + gelu with coalesced LDS epilogue.
// R9's regression was a rule-#20 scratch spill: the epilogue's oh-loop was
// `#pragma unroll 1`, making Y[] runtime-indexed (FETCH +93MB, WRITE +150MB
// = Y spill traffic). Fix: FULLY unroll the epilogue so all Y indices are
// compile-time. h bitwise-identical to R7/R9 (same arithmetic chain).
// ---------------------------------------------------------------------------
__global__ __launch_bounds__(256, 3) void up_kernel(
    const float* __restrict__ x, const float* __restrict__ Wup,
    const float* __restrict__ Aup, const float* __restrict__ Bup,
    const float* __restrict__ scale_up, const float* __restrict__ bias_up,
    float* __restrict__ h)
{
    // router: xs@0 (16384B) | wcs@16384 (17408B) | lp@33792 (4096B) |
    //         logits@37888 (1024B)  = 38912B
    // expert: wt@0 = [4 waves][64 p][36 i] fp32 (36864B) aliases xs..lp.
    __shared__ __align__(16) char smem[38912];
    float* xs     = (float*)smem;
    float* wcs    = (float*)(smem + 16384);
    float* lp     = (float*)(smem + 33792);
    float* logits = (float*)(smem + 37888);
    float* wt     = (float*)smem;
    __shared__ int   seli[TB1 * 2];
    __shared__ float selp[TB1 * 2];

    const int tid = threadIdx.x;
    const long long blockTok = (long long)blockIdx.x * TB1;

    // ---- stage x rows (verbatim) ----
    {
        const float* src = x + blockTok * 1024;
#pragma unroll
        for (int q = 0; q < TB1; ++q) {
            int flat = tid * 4 + q * 1024;
            *(float4*)&xs[flat] = ldg4(src + flat);
        }
    }

    // ---- router: logits = x . Wup^T (bitwise; T14 prefetch) ----
    float racc0[TB1] = {0.f, 0.f, 0.f, 0.f};
    float racc1[TB1] = {0.f, 0.f, 0.f, 0.f};
    const int e2 = tid & 31, jsl = tid >> 5;
    const int prow = tid >> 4, pcol = (tid & 15) * 4;

    float4 qw0 = ldg4(&Wup[(prow +  0) * 1024 + 0 + pcol]);
    float4 qw1 = ldg4(&Wup[(prow + 16) * 1024 + 0 + pcol]);
    float4 qw2 = ldg4(&Wup[(prow + 32) * 1024 + 0 + pcol]);
    float4 qw3 = ldg4(&Wup[(prow + 48) * 1024 + 0 + pcol]);

    for (int kc = 0; kc < 1024; kc += 64) {
        __syncthreads();
        *(float4*)&wcs[(prow +  0) * 68 + pcol] = qw0;
        *(float4*)&wcs[(prow + 16) * 68 + pcol] = qw1;
        *(float4*)&wcs[(prow + 32) * 68 + pcol] = qw2;
        *(float4*)&wcs[(prow + 48) * 68 + pcol] = qw3;
        {
            int nkc = (kc + 64 < 1024) ? kc + 64 : 0;  // last prefetch discarded
            qw0 = ldg4(&Wup[(prow +  0) * 1024 + nkc + pcol]);
            qw1 = ldg4(&Wup[(prow + 16) * 1024 + nkc + pcol]);
            qw2 = ldg4(&Wup[(prow + 32) * 1024 + nkc + pcol]);
            qw3 = ldg4(&Wup[(prow + 48) * 1024 + nkc + pcol]);
        }
        __syncthreads();
#pragma unroll
        for (int ks = 0; ks < 2; ++ks) {
            int kk = jsl * 8 + ks * 4;
            float4 w0 = *(float4*)&wcs[e2 * 68 + kk];
            float4 w1 = *(float4*)&wcs[(e2 + 32) * 68 + kk];
#pragma unroll
            for (int t = 0; t < TB1; ++t) {
                float4 xv = *(float4*)&xs[t * 1024 + kc + kk];
                racc0[t] += w0.x * xv.x + w0.y * xv.y + w0.z * xv.z + w0.w * xv.w;
                racc1[t] += w1.x * xv.x + w1.y * xv.y + w1.z * xv.z + w1.w * xv.w;
            }
        }
    }
#pragma unroll
    for (int t = 0; t < TB1; ++t) {
        racc0[t] += __shfl_xor(racc0[t], 32);
        racc1[t] += __shfl_xor(racc1[t], 32);
    }
    {
        const int wv = tid >> 6;
        if ((tid & 32) == 0) {
#pragma unroll
            for (int t = 0; t < TB1; ++t) {
                lp[(wv * TB1 + t) * 64 + e2]      = racc0[t];
                lp[(wv * TB1 + t) * 64 + e2 + 32] = racc1[t];
            }
        }
    }
    __syncthreads();
    logits[tid] = lp[0 * 256 + tid] + lp[1 * 256 + tid] + lp[2 * 256 + tid] + lp[3 * 256 + tid];
    __syncthreads();
    if (tid < TB1) {
        const float* lg = &logits[tid * 64];
        float v0 = -1e30f; int i0 = 0;
        for (int q = 0; q < 64; ++q) { float v = lg[q]; if (v > v0) { v0 = v; i0 = q; } }
        float v1 = -1e30f; int i1 = 0;
        for (int q = 0; q < 64; ++q) { if (q == i0) continue; float v = lg[q]; if (v > v1) { v1 = v; i1 = q; } }
        float r = expf(v1 - v0);
        float inv = 1.f / (1.f + r);
        seli[tid * 2] = i0; seli[tid * 2 + 1] = i1;
        selp[tid * 2] = inv; selp[tid * 2 + 1] = r * inv;
    }
    __syncthreads();

    // ---- experts: per-wave bf16x3 MFMA, 1 token/wave ----
    const float sc_up = scale_up[0];
    const int wv = tid >> 6, lane = tid & 63;
    const int m = lane & 15, quad = lane >> 4;
    const long long tok = blockTok + wv;
    float* wtw = wt + wv * 2304;     // [64 p][36 i] fp32 per wave

    // X fp32 fragments from xs (before wt aliases it)
    const float* xrow = &xs[wv * 1024];
    f4v xA0 = *(const f4v*)&xrow[(0 * 16 + m) * 32 + quad * 8];
    f4v xA1 = *(const f4v*)&xrow[(0 * 16 + m) * 32 + quad * 8 + 4];
    f4v xB0 = *(const f4v*)&xrow[(1 * 16 + m) * 32 + quad * 8];
    f4v xB1 = *(const f4v*)&xrow[(1 * 16 + m) * 32 + quad * 8 + 4];
    __syncthreads();   // xs dead; wt region free for expert phase

    const f4v zf = {0.f, 0.f, 0.f, 0.f};
    f4v Y[16];   // [ot 0..3][pt 0..3]
#pragma unroll
    for (int q = 0; q < 16; ++q) Y[q] = zf;

#pragma unroll 1
    for (int ke = 0; ke < 2; ++ke) {
        const int ex = seli[wv * 2 + ke];
        const float pw = selp[wv * 2 + ke];
        const float* A = Aup + (long long)ex * 2048;  // [64 o][32 i]
        const float* B = Bup + (long long)ex * 2048;  // [64 p][32 j]

        S3 x0 = split8(xA0, xA1);
        S3 x1 = split8(xB0, xB1);

        // ---- stage 1: W[i][p] = sum_j X[i][j] B[p][j]  (K=32) ----
        f4v wd[8];   // [mt 0..1][pt 0..3]
#pragma unroll
        for (int pt = 0; pt < 4; ++pt) {
            int base = (pt * 16 + m) * 32 + quad * 8;
            S3 bs = split8(*(const f4v*)(B + base), *(const f4v*)(B + base + 4));
            wd[0 * 4 + pt] = mfma6(x0, bs, zf);
            wd[1 * 4 + pt] = mfma6(x1, bs, zf);
        }
        // write (pw*W)^T fp32: lane holds W[i = mt*16+quad*4+r][p = pt*16+m]
        {
            const f4v pwv = {pw, pw, pw, pw};
#pragma unroll
            for (int mt = 0; mt < 2; ++mt)
#pragma unroll
                for (int pt = 0; pt < 4; ++pt) {
                    f4v w = wd[mt * 4 + pt] * pwv;
                    *(f4v*)&wtw[(pt * 16 + m) * 36 + mt * 16 + quad * 4] = w;
                }
        }

        // ---- stage 2: Y[o][p] += sum_i A[o][i] (pw*W)[i][p]  (K=32) ----
#pragma unroll
        for (int pth = 0; pth < 2; ++pth) {
            int p0 = (pth * 2 + 0) * 16 + m;
            int p1 = (pth * 2 + 1) * 16 + m;
            S3 w0 = split8(*(const f4v*)&wtw[p0 * 36 + quad * 8],
                           *(const f4v*)&wtw[p0 * 36 + quad * 8 + 4]);
            S3 w1 = split8(*(const f4v*)&wtw[p1 * 36 + quad * 8],
                           *(const f4v*)&wtw[p1 * 36 + quad * 8 + 4]);
#pragma unroll
            for (int ot = 0; ot < 4; ++ot) {
                int abase = (ot * 16 + m) * 32 + quad * 8;
                S3 as = split8(*(const f4v*)(A + abase), *(const f4v*)(A + abase + 4));
                Y[ot * 4 + pth * 2 + 0] = mfma6(as, w0, Y[ot * 4 + pth * 2 + 0]);
                Y[ot * 4 + pth * 2 + 1] = mfma6(as, w1, Y[ot * 4 + pth * 2 + 1]);
            }
        }
    }

    // ---- epilogue: coalesced via per-wave LDS transpose, FULLY UNROLLED ----
    // (rule #20: every Y index must be compile-time; R9's `unroll 1` spilled
    // Y to scratch). Same-wave ds ordering; per-element math identical.
    {
        float* hrow = h + tok * 4096;
#pragma unroll
        for (int oh = 0; oh < 2; ++oh) {
#pragma unroll
            for (int oti = 0; oti < 2; ++oti) {
#pragma unroll
                for (int r = 0; r < 4; ++r) {
                    int ol = oti * 16 + quad * 4 + r;
#pragma unroll
                    for (int pt = 0; pt < 4; ++pt)
                        wtw[ol * 68 + pt * 16 + m] = Y[(oh * 2 + oti) * 4 + pt][r] * sc_up;
                }
            }
#pragma unroll
            for (int it = 0; it < 8; ++it) {
                int fl = it * 256 + lane * 4;
                int ol = fl >> 6, p = fl & 63;
                f4v v = *(const f4v*)&wtw[ol * 68 + p];
                float4 bb = ldg4(&bias_up[oh * 2048 + fl]);
                f4v g;
                float z;
                z = v[0] + bb.x; g[0] = 0.5f * z * (1.0f + erff(z * 0.70710678118654752f));
                z = v[1] + bb.y; g[1] = 0.5f * z * (1.0f + erff(z * 0.70710678118654752f));
                z = v[2] + bb.z; g[2] = 0.5f * z * (1.0f + erff(z * 0.70710678118654752f));
                z = v[3] + bb.w; g[3] = 0.5f * z * (1.0f + erff(z * 0.70710678118654752f));
                *(f4v*)&hrow[oh * 2048 + fl] = g;
            }
        }
    }
}

// ---------------------------------------------------------------------------
// Kernel 2: down router + down experts (bf16 MFMA, per-wave)
// [VERBATIM R0 baseline — measured ~187.5 us]
// ---------------------------------------------------------------------------
__global__ __launch_bounds__(256, 2) void down_kernel(
    const float* __restrict__ h,        // [N][4096]
    const float* __restrict__ Wdn,      // [64][4096]
    const float* __restrict__ Adn,      // [64][32][64]
    const float* __restrict__ Bdn,      // [64][32][64]
    const float* __restrict__ scale_dn, // [1]
    const float* __restrict__ bias_dn,  // [1024]
    float* __restrict__ out)            // [N][1024]
{
    __shared__ __align__(16) float wcs[64 * 68];    // 17.4 KB
    __shared__ __align__(16) float hcs[16 * 68];    // 4.3 KB
    __shared__ __align__(16) float lp[4 * 16 * 64]; // 16.4 KB
    __shared__ __align__(16) float logits[TB2 * 64];
    __shared__ __align__(16) short wt[4][32 * 72];  // per-wave W^T bf16 [p][i]
    __shared__ int   seli[TB2 * 2];
    __shared__ float selp[TB2 * 2];

    const int tid = threadIdx.x;
    const long long tokbase = (long long)blockIdx.x * TB2;

    // ---- down router: 4 experts per thread, k-slice = one float4 ----
    const int e4 = tid & 15, jsl = tid >> 4; // jsl 0..15
    float r0[16], r1[16], r2[16], r3[16];
#pragma unroll
    for (int t = 0; t < 16; ++t) { r0[t] = 0.f; r1[t] = 0.f; r2[t] = 0.f; r3[t] = 0.f; }

    for (int kc = 0; kc < 4096; kc += 64) {
        __syncthreads();
#pragma unroll
        for (int r = 0; r < 4; ++r) {
            int row = (tid >> 4) + r * 16;
            int col = (tid & 15) * 4;
            *(float4*)&wcs[row * 68 + col] = ldg4(&Wdn[row * 4096 + kc + col]);
        }
        {
            int t = tid >> 4, c = (tid & 15) * 4;
            *(float4*)&hcs[t * 68 + c] = ldg4(&h[(tokbase + t) * 4096 + kc + c]);
        }
        __syncthreads();
        const int kk = jsl * 4;
        float4 w0 = *(float4*)&wcs[(e4)      * 68 + kk];
        float4 w1 = *(float4*)&wcs[(e4 + 16) * 68 + kk];
        float4 w2 = *(float4*)&wcs[(e4 + 32) * 68 + kk];
        float4 w3 = *(float4*)&wcs[(e4 + 48) * 68 + kk];
#pragma unroll
        for (int t = 0; t < 16; ++t) {
            float4 hv = *(float4*)&hcs[t * 68 + kk];
            r0[t] += w0.x * hv.x + w0.y * hv.y + w0.z * hv.z + w0.w * hv.w;
            r1[t] += w1.x * hv.x + w1.y * hv.y + w1.z * hv.z + w1.w * hv.w;
            r2[t] += w2.x * hv.x + w2.y * hv.y + w2.z * hv.z + w2.w * hv.w;
            r3[t] += w3.x * hv.x + w3.y * hv.y + w3.z * hv.z + w3.w * hv.w;
        }
    }
    // reduce over the wave's 4 k-slices (lanes xor 16, 32)
#pragma unroll
    for (int t = 0; t < 16; ++t) {
        r0[t] += __shfl_xor(r0[t], 16); r0[t] += __shfl_xor(r0[t], 32);
        r1[t] += __shfl_xor(r1[t], 16); r1[t] += __shfl_xor(r1[t], 32);
        r2[t] += __shfl_xor(r2[t], 16); r2[t] += __shfl_xor(r2[t], 32);
        r3[t] += __shfl_xor(r3[t], 16); r3[t] += __shfl_xor(r3[t], 32);
    }
    {
        const int wv = tid >> 6, g = (tid >> 4) & 3;
        float* dst = &lp[wv * 1024];
        if (g == 0) {
#pragma unroll
            for (int t = 0; t < 16; ++t) dst[t * 64 + e4] = r0[t];
        } else if (g == 1) {
#pragma unroll
            for (int t = 0; t < 16; ++t) dst[t * 64 + 16 + e4] = r1[t];
        } else if (g == 2) {
#pragma unroll
            for (int t = 0; t < 16; ++t) dst[t * 64 + 32 + e4] = r2[t];
        } else {
#pragma unroll
            for (int t = 0; t < 16; ++t) dst[t * 64 + 48 + e4] = r3[t];
        }
    }
    __syncthreads();
#pragma unroll
    for (int q = 0; q < 4; ++q) {
        int pair = tid + q * 256;
        logits[pair] = lp[0 * 1024 + pair] + lp[1 * 1024 + pair] +
                       lp[2 * 1024 + pair] + lp[3 * 1024 + pair];
    }
    __syncthreads();
    if (tid < TB2) {
        const float* lg = &logits[tid * 64];
        float v0 = -1e30f; int i0 = 0;
        for (int q = 0; q < 64; ++q) { float v = lg[q]; if (v > v0) { v0 = v; i0 = q; } }
        float v1 = -1e30f; int i1 = 0;
        for (int q = 0; q < 64; ++q) { if (q == i0) continue; float v = lg[q]; if (v > v1) { v1 = v; i1 = q; } }
        float r = expf(v1 - v0);
        float inv = 1.f / (1.f + r);
        seli[tid * 2] = i0; seli[tid * 2 + 1] = i1;
        selp[tid * 2] = inv; selp[tid * 2 + 1] = r * inv;
    }
    __syncthreads();

    // ---- down experts: per-wave MFMA, no barriers ----
    const float sc_dn = scale_dn[0];
    const int wv = tid >> 6;
    const int lane = tid & 63;
    const int m = lane & 15, quad = lane >> 4;
    short* wtw = &wt[wv][0]; // [32 p][72 i] bf16

    const f4v zf = {0.f, 0.f, 0.f, 0.f};

#pragma unroll 1
    for (int tt = 0; tt < 4; ++tt) {
        const int t = wv * 4 + tt;
        const long long tok = tokbase + t;
        const float* xrow = h + tok * 4096; // X[64 i][64 j], j contiguous

        s8v xf[8];
#pragma unroll
        for (int mt = 0; mt < 4; ++mt)
#pragma unroll
            for (int ks = 0; ks < 2; ++ks) {
                int base = (mt * 16 + m) * 64 + ks * 32 + quad * 8;
                xf[mt * 2 + ks] = pack8(ldg4(xrow + base), ldg4(xrow + base + 4));
            }

        f4v y00 = zf, y01 = zf, y10 = zf, y11 = zf;

        for (int ke = 0; ke < 2; ++ke) {
            const int ex = seli[t * 2 + ke];
            const float pw = selp[t * 2 + ke];
            const float* A = Adn + ex * 2048; // [32 o][64 i]
            const float* B = Bdn + ex * 2048; // [32 p][64 j]

            // ---- stage 1: W[i][p] = sum_j X[i][j] * B[p][j] ----
            f4v wd[8];
#pragma unroll
            for (int ks = 0; ks < 2; ++ks) {
                s8v bf0, bf1;
                {
                    int base = (0 * 16 + m) * 64 + ks * 32 + quad * 8;
                    bf0 = pack8(ldg4(B + base), ldg4(B + base + 4));
                    base = (1 * 16 + m) * 64 + ks * 32 + quad * 8;
                    bf1 = pack8(ldg4(B + base), ldg4(B + base + 4));
                }
#pragma unroll
                for (int mt = 0; mt < 4; ++mt) {
                    wd[mt * 2 + 0] = __builtin_amdgcn_mfma_f32_16x16x32_bf16(
                        xf[mt * 2 + ks], bf0, ks == 0 ? zf : wd[mt * 2 + 0], 0, 0, 0);
                    wd[mt * 2 + 1] = __builtin_amdgcn_mfma_f32_16x16x32_bf16(
                        xf[mt * 2 + ks], bf1, ks == 0 ? zf : wd[mt * 2 + 1], 0, 0, 0);
                }
            }
#pragma unroll
            for (int mt = 0; mt < 4; ++mt)
#pragma unroll
                for (int pt = 0; pt < 2; ++pt) {
                    f4v w = wd[mt * 2 + pt];
                    s4v s;
                    s[0] = f2b(w[0] * pw); s[1] = f2b(w[1] * pw);
                    s[2] = f2b(w[2] * pw); s[3] = f2b(w[3] * pw);
                    *(s4v*)&wtw[(pt * 16 + m) * 72 + mt * 16 + quad * 4] = s;
                }

            // ---- stage 2: Y[o][p] += sum_i A[o][i] * (pw*W)[i][p] ----
#pragma unroll
            for (int ks = 0; ks < 2; ++ks) {
                s8v wb0 = *(s8v*)&wtw[(0 * 16 + m) * 72 + ks * 32 + quad * 8];
                s8v wb1 = *(s8v*)&wtw[(1 * 16 + m) * 72 + ks * 32 + quad * 8];
                s8v af0, af1;
                {
                    int base = (0 * 16 + m) * 64 + ks * 32 + quad * 8;
                    af0 = pack8(ldg4(A + base), ldg4(A + base + 4));
                    base = (1 * 16 + m) * 64 + ks * 32 + quad * 8;
                    af1 = pack8(ldg4(A + base), ldg4(A + base + 4));
                }
                y00 = __builtin_amdgcn_mfma_f32_16x16x32_bf16(af0, wb0, y00, 0, 0, 0);
                y01 = __builtin_amdgcn_mfma_f32_16x16x32_bf16(af0, wb1, y01, 0, 0, 0);
                y10 = __builtin_amdgcn_mfma_f32_16x16x32_bf16(af1, wb0, y10, 0, 0, 0);
                y11 = __builtin_amdgcn_mfma_f32_16x16x32_bf16(af1, wb1, y11, 0, 0, 0);
            }
        }

        float* orow = out + tok * 1024;
#pragma unroll
        for (int r = 0; r < 4; ++r) {
            int o0 = quad * 4 + r;
            int f00 = o0 * 32 + m;
            orow[f00]            = y00[r] * sc_dn + bias_dn[f00];
            orow[f00 + 16]       = y01[r] * sc_dn + bias_dn[f00 + 16];
            int f10 = (o0 + 16) * 32 + m;
            orow[f10]            = y10[r] * sc_dn + bias_dn[f10];
            orow[f10 + 16]       = y11[r] * sc_dn + bias_dn[f10 + 16];
        }
    }
}

extern "C" void kernel_launch(void* const* d_in, const int* in_sizes, int n_in,
                              void* d_out, int out_size, void* d_ws, size_t ws_size,
                              hipStream_t stream) {
    const float* x   = (const float*)d_in[0];
    const float* Wup = (const float*)d_in[1];
    const float* Aup = (const float*)d_in[2];
    const float* Bup = (const float*)d_in[3];
    const float* scu = (const float*)d_in[4];
    const float* biu = (const float*)d_in[5];
    const float* Wdn = (const float*)d_in[6];
    const float* Adn = (const float*)d_in[7];
    const float* Bdn = (const float*)d_in[8];
    const float* scd = (const float*)d_in[9];
    const float* bid = (const float*)d_in[10];
    float* out = (float*)d_out;
    float* h   = (float*)d_ws;   // [N][4096] fp32 = 128 MB for N=8192

    const int N = in_sizes[0] / 1024;

    hipLaunchKernelGGL(up_kernel, dim3(N / TB1), dim3(256), 0, stream,
                       x, Wup, Aup, Bup, scu, biu, h);
    hipLaunchKernelGGL(down_kernel, dim3(N / TB2), dim3(256), 0, stream,
                       h, Wdn, Adn, Bdn, scd, bid, out);
}